// Round 11
// baseline (57.491 us; speedup 1.0000x reference)
//
#include <hip/hip_runtime.h>
#include <math.h>

// GraphGenerator: radius-graph adjacency, OR over {0,0.25,0.5,0.75}*domain
// wrapped shifts, diagonal excluded. Output [N,N] int32 0/1. Single kernel.
//
// Golden ("ref=np") — PROVEN in R7 (absmax 0):
//   sq   = ((x*x) + (y*y)) + (z*z)          separately rounded (contract off!)
//   dot  = fma(z,z', fma(y,y', rn(x*x')))   sgemm sequential-k FMA chain
//   d2   = rn(rn(sq_i + sq_j) - rn(2*dot))
//   pred = d2 <= 0.01f ; wrap = fmodf(rn(x + rn(f*d)), d)
//
// Min-image prefilter (R8-proven): min-image d2 lower-bounds all variants and
// is achieved by one of them (seam argument); fast/golden chains differ by
// < 3e-5 worst case, so outside the +-3e-5 band the fast f32 decision is
// identical to the golden OR. In-band groups recompute the exact R7 chain.
// R10 lesson: NO nontemporal stores — plain stores ride the L2 writeback
// path at fill-kernel speed; nt streaming regressed 13%.
//
// Whole kernel is compiled contract(off); the i-tile staging and band path
// need it for golden-chain fidelity, the fast path merely loses one fma.

__global__ __launch_bounds__(256) void gg_adj_kernel(
    const float* __restrict__ pos, const float* __restrict__ dom,
    int* __restrict__ out, int n)
{
#pragma clang fp contract(off)
    const int tid = threadIdx.x;
    const int tj = tid & 63;
    const int ti = tid >> 6;
    const int jbase = blockIdx.x * 256 + tj * 4;
    const int ibase = blockIdx.y * 32;
    const bool hasdiag = ((blockIdx.y >> 3) == blockIdx.x);

    const float dom0 = dom[0], dom1 = dom[1], dom2 = dom[2];

    // Stage i-tile: 32 threads compute 4 shift variants (exact golden chain).
    __shared__ float4 si[32][4];   // [i][variant] = (sx,sy,sz,sq)
    if (tid < 32) {
        const int i = ibase + tid;
        const float x = pos[3 * i + 0];
        const float y = pos[3 * i + 1];
        const float z = pos[3 * i + 2];
#pragma unroll
        for (int k = 0; k < 4; ++k) {
            float sx, sy, sz;
            if (k == 0) {
                sx = x; sy = y; sz = z;
            } else {
                const float f = 0.25f * (float)k;     // exact
                sx = fmodf(x + f * dom0, dom0);
                sy = fmodf(y + f * dom1, dom1);
                sz = fmodf(z + f * dom2, dom2);
            }
            const float sq = ((sx * sx) + (sy * sy)) + (sz * sz);
            si[tid][k] = make_float4(sx, sy, sz, sq);
        }
    }

    // j-side: raw coords of 4 points (12 consecutive floats, 16B-aligned).
    const float4 j0 = *(const float4*)&pos[3 * jbase + 0];
    const float4 j1 = *(const float4*)&pos[3 * jbase + 4];
    const float4 j2 = *(const float4*)&pos[3 * jbase + 8];
    float jx[4], jy[4], jz[4];
    jx[0] = j0.x; jy[0] = j0.y; jz[0] = j0.z;
    jx[1] = j0.w; jy[1] = j1.x; jz[1] = j1.y;
    jx[2] = j1.z; jy[2] = j1.w; jz[2] = j2.x;
    jx[3] = j2.y; jy[3] = j2.z; jz[3] = j2.w;

    __syncthreads();

    const float RR  = 0.01f;       // f32(0.1*0.1)
    const float EPS = 3e-5f;       // band half-width

    for (int iter = 0; iter < 8; ++iter) {
        const int irow = iter * 4 + ti;
        const int i = ibase + irow;
        const float4 i0 = si[irow][0];       // LDS broadcast, raw coords

        float d2m[4];
#pragma unroll
        for (int p = 0; p < 4; ++p) {
            const float dxv = i0.x - jx[p];
            const float dyv = i0.y - jy[p];
            const float dzv = i0.z - jz[p];
            const float mx = fminf(fabsf(dxv), dom0 - fabsf(dxv));
            const float my = fminf(fabsf(dyv), dom1 - fabsf(dyv));
            const float mz = fminf(fabsf(dzv), dom2 - fabsf(dzv));
            d2m[p] = ((mx * mx) + (my * my)) + (mz * mz);
        }

        bool b0 = d2m[0] <= RR, b1 = d2m[1] <= RR,
             b2 = d2m[2] <= RR, b3 = d2m[3] <= RR;

        const bool band = (fabsf(d2m[0] - RR) <= EPS) |
                          (fabsf(d2m[1] - RR) <= EPS) |
                          (fabsf(d2m[2] - RR) <= EPS) |
                          (fabsf(d2m[3] - RR) <= EPS);
        if (__builtin_expect(band, 0)) {
            // Rare: exact R7 golden chain, all 4 pairs, all 4 variants.
            bool bb[4] = {false, false, false, false};
#pragma unroll 1
            for (int k = 0; k < 4; ++k) {
                const float4 iv = si[irow][k];
                const float f = 0.25f * (float)k;
#pragma unroll
                for (int p = 0; p < 4; ++p) {
                    float sx, sy, sz;
                    if (k == 0) {
                        sx = jx[p]; sy = jy[p]; sz = jz[p];
                    } else {
                        sx = fmodf(jx[p] + f * dom0, dom0);
                        sy = fmodf(jy[p] + f * dom1, dom1);
                        sz = fmodf(jz[p] + f * dom2, dom2);
                    }
                    const float jsq = ((sx * sx) + (sy * sy)) + (sz * sz);
                    float dot = __builtin_fmaf(iv.z, sz,
                                __builtin_fmaf(iv.y, sy, iv.x * sx));
                    float d2 = (iv.w + jsq) - (2.0f * dot);
                    if (d2 <= RR) bb[p] = true;
                }
            }
            b0 = bb[0]; b1 = bb[1]; b2 = bb[2]; b3 = bb[3];
        }

        int4 res;
        res.x = b0 ? 1 : 0;
        res.y = b1 ? 1 : 0;
        res.z = b2 ? 1 : 0;
        res.w = b3 ? 1 : 0;
        if (hasdiag) {
            if (i == jbase + 0) res.x = 0;
            if (i == jbase + 1) res.y = 0;
            if (i == jbase + 2) res.z = 0;
            if (i == jbase + 3) res.w = 0;
        }
        *reinterpret_cast<int4*>(&out[(size_t)i * n + jbase]) = res;
    }
}

extern "C" void kernel_launch(void* const* d_in, const int* in_sizes, int n_in,
                              void* d_out, int out_size, void* d_ws, size_t ws_size,
                              hipStream_t stream) {
    const float* pos = (const float*)d_in[0];   // [N,3] float32
    const float* dom = (const float*)d_in[1];   // [3] float32
    const int n = in_sizes[0] / 3;              // 8192

    int* out = (int*)d_out;                     // [N,N] int32 0/1

    dim3 grid(n / 256, n / 32);                 // (32, 256)
    gg_adj_kernel<<<grid, 256, 0, stream>>>(pos, dom, out, n);
}

// Round 12
// 52.852 us; speedup vs baseline: 1.0878x; 1.0878x over previous
//
#include <hip/hip_runtime.h>
#include <math.h>

// GraphGenerator: radius-graph adjacency, OR over {0,0.25,0.5,0.75}*domain
// wrapped shifts, diagonal excluded. Output [N,N] int32 0/1.
//
// Golden ("ref=np") — PROVEN in R7 (absmax 0):
//   sq   = ((x*x) + (y*y)) + (z*z)          separately rounded (contract off!)
//   dot  = fma(z,z', fma(y,y', rn(x*x')))   sgemm sequential-k FMA chain
//   d2   = rn(rn(sq_i + sq_j) - rn(2*dot))
//   pred = d2 <= 0.01f ; wrap = fmodf(rn(x + rn(f*d)), d)
//
// Min-image prefilter (R8-proven, 51.0us): min-image d2 lower-bounds all
// variants and is achieved by one of them (seam argument); fast/golden chains
// differ < 3e-5, so outside the +-3e-5 band the fast f32 decision equals the
// golden OR; in-band pairs rerun the exact R7 chain from sp.
// R8->R10/R11 lesson: keep fast path contractible (contract(off) only where
// golden fidelity requires), plain stores, per-pair band branch.
// R12 change: ONE BLOCK = ONE OUTPUT ROW -> stores are one contiguous 32KB
// run per block (R8's 1KB/32KB-stride fragments ran at 5.3 vs fill's 7.0 TB/s).

__global__ __launch_bounds__(256) void gg_shift_kernel(
    const float* __restrict__ pos, const float* __restrict__ dom,
    float4* __restrict__ sp, int n)
{
#pragma clang fp contract(off)
    int i = blockIdx.x * blockDim.x + threadIdx.x;
    if (i >= n) return;
    float x = pos[3 * i + 0];
    float y = pos[3 * i + 1];
    float z = pos[3 * i + 2];
    float dx = dom[0], dy = dom[1], dz = dom[2];
#pragma unroll
    for (int k = 0; k < 4; ++k) {
        float sx, sy, sz;
        if (k == 0) {
            sx = x; sy = y; sz = z;
        } else {
            float f = 0.25f * (float)k;
            sx = fmodf(x + f * dx, dx);
            sy = fmodf(y + f * dy, dy);
            sz = fmodf(z + f * dz, dz);
        }
        float sq = ((sx * sx) + (sy * sy)) + (sz * sz);
        sp[(size_t)i * 4 + k] = make_float4(sx, sy, sz, sq);
    }
}

// One block per output row: block y vs all n columns, 8 passes of 1024 cols.
__global__ __launch_bounds__(256) void gg_adj_row_kernel(
    const float* __restrict__ pos, const float4* __restrict__ sp,
    const float* __restrict__ dom, int* __restrict__ out, int n)
{
    const int y = blockIdx.x;            // output row == i point (uniform)
    const int tid = threadIdx.x;

    // i-side raw coords: wave-uniform scalar loads.
    const float ix = pos[3 * y + 0];
    const float iy = pos[3 * y + 1];
    const float iz = pos[3 * y + 2];
    const float dom0 = dom[0], dom1 = dom[1], dom2 = dom[2];

    const float RR  = 0.01f;             // f32(0.1*0.1)
    const float LO  = 0.01f - 3e-5f;
    const float HI  = 0.01f + 3e-5f;

    int* orow = &out[(size_t)y * n];

    for (int pass = 0; pass < 8; ++pass) {
        const int jbase = pass * 1024 + tid * 4;

        // 4 j-points' raw coords (12 consecutive floats, 16B aligned).
        const float4 j0 = *(const float4*)&pos[3 * jbase + 0];
        const float4 j1 = *(const float4*)&pos[3 * jbase + 4];
        const float4 j2 = *(const float4*)&pos[3 * jbase + 8];
        float jx[4], jy[4], jz[4];
        jx[0] = j0.x; jy[0] = j0.y; jz[0] = j0.z;
        jx[1] = j0.w; jy[1] = j1.x; jz[1] = j1.y;
        jx[2] = j1.z; jy[2] = j1.w; jz[2] = j2.x;
        jx[3] = j2.y; jy[3] = j2.z; jz[3] = j2.w;

        int4 res;
        int* r = &res.x;
#pragma unroll
        for (int p = 0; p < 4; ++p) {
            // fast path: f32 min-image d2 (contraction fine, margin absorbs)
            const float ax = fabsf(ix - jx[p]);
            const float ay = fabsf(iy - jy[p]);
            const float az = fabsf(iz - jz[p]);
            const float mx = fminf(ax, dom0 - ax);
            const float my = fminf(ay, dom1 - ay);
            const float mz = fminf(az, dom2 - az);
            const float d2m = mx * mx + my * my + mz * mz;
            bool b = d2m <= RR;
            if (__builtin_expect(d2m >= LO && d2m <= HI, 0)) {
                // band: exact golden chain over all 4 variants (from sp)
#pragma clang fp contract(off)
                b = false;
#pragma unroll 1
                for (int k = 0; k < 4; ++k) {
                    const float4 iv = sp[(size_t)y * 4 + k];
                    const float4 jv = sp[(size_t)(jbase + p) * 4 + k];
                    float dot = __builtin_fmaf(iv.z, jv.z,
                                __builtin_fmaf(iv.y, jv.y, iv.x * jv.x));
                    float d2 = (iv.w + jv.w) - (2.0f * dot);
                    if (d2 <= RR) b = true;
                }
            }
            r[p] = (b && (y != jbase + p)) ? 1 : 0;
        }
        *reinterpret_cast<int4*>(&orow[jbase]) = res;   // contiguous 4KB/wave
    }
}

extern "C" void kernel_launch(void* const* d_in, const int* in_sizes, int n_in,
                              void* d_out, int out_size, void* d_ws, size_t ws_size,
                              hipStream_t stream) {
    const float* pos = (const float*)d_in[0];   // [N,3] float32
    const float* dom = (const float*)d_in[1];   // [3] float32
    const int n = in_sizes[0] / 3;              // 8192

    float4* sp = (float4*)d_ws;                 // [N][4] float4 = 512 KB
    int* out = (int*)d_out;                     // [N,N] int32 0/1

    gg_shift_kernel<<<(n + 255) / 256, 256, 0, stream>>>(pos, dom, sp, n);

    gg_adj_row_kernel<<<n, 256, 0, stream>>>(pos, sp, dom, out, n);
}

// Round 13
// 50.316 us; speedup vs baseline: 1.1426x; 1.0504x over previous
//
#include <hip/hip_runtime.h>
#include <math.h>

// GraphGenerator: radius-graph adjacency, OR over {0,0.25,0.5,0.75}*domain
// wrapped shifts, diagonal excluded. Output [N,N] int32 0/1.
//
// Golden ("ref=np") — PROVEN in R7 (absmax 0):
//   sq   = ((x*x) + (y*y)) + (z*z)          separately rounded (contract off!)
//   dot  = fma(z,z', fma(y,y', rn(x*x')))   sgemm sequential-k FMA chain
//   d2   = rn(rn(sq_i + sq_j) - rn(2*dot))
//   pred = d2 <= 0.01f ; wrap = fmodf(rn(x + rn(f*d)), d)
//
// Min-image prefilter (R8-proven, 51.0us): min-image d2 lower-bounds all
// variants and is achieved by one of them (seam argument); fast/golden chains
// differ < 3e-5, so outside the +-3e-5 band the fast f32 decision equals the
// golden OR; in-band pairs rerun the exact R7 chain from sp.
// R10-R12 lessons: store pattern (1KB frags vs 32KB runs) doesn't matter;
// NT stores don't matter; epilogue restructure + whole-kernel contract(off)
// regressed. R13 change vs R8: (1) accumulate all 8 int4 results, then issue
// 8 back-to-back stores (store MLP like the 7TB/s fill kernel); (2) diagonal
// fixup hoisted to the 32/8192 blocks that contain it.

__global__ __launch_bounds__(256) void gg_shift_kernel(
    const float* __restrict__ pos, const float* __restrict__ dom,
    float4* __restrict__ sp, int n)
{
#pragma clang fp contract(off)
    int i = blockIdx.x * blockDim.x + threadIdx.x;
    if (i >= n) return;
    float x = pos[3 * i + 0];
    float y = pos[3 * i + 1];
    float z = pos[3 * i + 2];
    float dx = dom[0], dy = dom[1], dz = dom[2];
#pragma unroll
    for (int k = 0; k < 4; ++k) {
        float sx, sy, sz;
        if (k == 0) {
            sx = x; sy = y; sz = z;
        } else {
            float f = 0.25f * (float)k;
            sx = fmodf(x + f * dx, dx);
            sy = fmodf(y + f * dy, dy);
            sz = fmodf(z + f * dz, dz);
        }
        float sq = ((sx * sx) + (sy * sy)) + (sz * sz);
        sp[(size_t)i * 4 + k] = make_float4(sx, sy, sz, sq);
    }
}

// Tile: 32 i-rows x 256 j-cols per 256-thread block (R8 structure).
__global__ __launch_bounds__(256) void gg_adj_kernel(
    const float4* __restrict__ sp, const float* __restrict__ dom,
    int* __restrict__ out, int n)
{
    const int tid = threadIdx.x;
    const int tj = tid & 63;
    const int ti = tid >> 6;
    const int jbase = blockIdx.x * 256 + tj * 4;
    const int ibase = blockIdx.y * 32;
    const bool hasdiag = ((blockIdx.y >> 3) == blockIdx.x);

    const float dom0 = dom[0], dom1 = dom[1], dom2 = dom[2];

    __shared__ float4 si[32][4];   // i-tile: 4 variants (slow path needs all)
    for (int t = tid; t < 128; t += 256)
        si[t >> 2][t & 3] = sp[(size_t)(ibase + (t >> 2)) * 4 + (t & 3)];

    float4 jd0[4];                 // j-side raw coords (variant 0)
#pragma unroll
    for (int p = 0; p < 4; ++p)
        jd0[p] = sp[(size_t)(jbase + p) * 4 + 0];

    __syncthreads();

    const float RR = 0.01f;          // f32(0.1*0.1)
    const float LO = 0.01f - 3e-5f;  // fast-accept below
    const float HI = 0.01f + 3e-5f;  // fast-reject above

    int4 resbuf[8];                  // all results, then burst-store

#pragma unroll
    for (int iter = 0; iter < 8; ++iter) {
        const int irow = iter * 4 + ti;
        const float4 i0 = si[irow][0];       // LDS broadcast, raw coords

        int* r = &resbuf[iter].x;
#pragma unroll
        for (int p = 0; p < 4; ++p) {
            // fast path: f32 min-image d2 (contraction fine, margin absorbs)
            const float ax = fabsf(i0.x - jd0[p].x);
            const float ay = fabsf(i0.y - jd0[p].y);
            const float az = fabsf(i0.z - jd0[p].z);
            const float mx = fminf(ax, dom0 - ax);
            const float my = fminf(ay, dom1 - ay);
            const float mz = fminf(az, dom2 - az);
            const float d2m = mx * mx + my * my + mz * mz;
            bool b = d2m <= RR;
            if (__builtin_expect(d2m >= LO && d2m <= HI, 0)) {
                // band: exact golden chain over all 4 variants (R7-proven)
#pragma clang fp contract(off)
                b = false;
#pragma unroll 1
                for (int k = 0; k < 4; ++k) {
                    const float4 iv = si[irow][k];
                    const float4 jv = sp[(size_t)(jbase + p) * 4 + k];
                    float dot = __builtin_fmaf(iv.z, jv.z,
                                __builtin_fmaf(iv.y, jv.y, iv.x * jv.x));
                    float d2 = (iv.w + jv.w) - (2.0f * dot);
                    if (d2 <= RR) b = true;
                }
            }
            r[p] = b ? 1 : 0;
        }
    }

    // Rare diagonal fixup (32 of 8192 blocks; i == jbase+p for one lane/iter).
    if (hasdiag) {
#pragma unroll
        for (int iter = 0; iter < 8; ++iter) {
            const int i = ibase + iter * 4 + ti;
            if (i == jbase + 0) resbuf[iter].x = 0;
            if (i == jbase + 1) resbuf[iter].y = 0;
            if (i == jbase + 2) resbuf[iter].z = 0;
            if (i == jbase + 3) resbuf[iter].w = 0;
        }
    }

    // Burst: 8 back-to-back dwordx4 stores (deep store MLP).
#pragma unroll
    for (int iter = 0; iter < 8; ++iter) {
        const int i = ibase + iter * 4 + ti;
        *reinterpret_cast<int4*>(&out[(size_t)i * n + jbase]) = resbuf[iter];
    }
}

extern "C" void kernel_launch(void* const* d_in, const int* in_sizes, int n_in,
                              void* d_out, int out_size, void* d_ws, size_t ws_size,
                              hipStream_t stream) {
    const float* pos = (const float*)d_in[0];   // [N,3] float32
    const float* dom = (const float*)d_in[1];   // [3] float32
    const int n = in_sizes[0] / 3;              // 8192

    float4* sp = (float4*)d_ws;                 // [N][4] float4 = 512 KB
    int* out = (int*)d_out;                     // [N,N] int32 0/1

    gg_shift_kernel<<<(n + 255) / 256, 256, 0, stream>>>(pos, dom, sp, n);

    dim3 grid(n / 256, n / 32);                 // (32, 256)
    gg_adj_kernel<<<grid, 256, 0, stream>>>(sp, dom, out, n);
}

// Round 14
// 47.735 us; speedup vs baseline: 1.2044x; 1.0541x over previous
//
#include <hip/hip_runtime.h>
#include <math.h>

// GraphGenerator: radius-graph adjacency, OR over {0,0.25,0.5,0.75}*domain
// wrapped shifts, diagonal excluded. Output [N,N] int32 0/1.
//
// Golden ("ref=np") — PROVEN in R7 (absmax 0):
//   sq   = ((x*x) + (y*y)) + (z*z)          separately rounded (contract off!)
//   dot  = fma(z,z', fma(y,y', rn(x*x')))   sgemm sequential-k FMA chain
//   d2   = rn(rn(sq_i + sq_j) - rn(2*dot))
//   pred = d2 <= 0.01f ; wrap = fmodf(rn(x + rn(f*d)), d)
//
// Min-image prefilter (R8-proven): min-image d2 lower-bounds all variants and
// is achieved by one of them (seam argument); fast/golden chains differ
// < 3e-5, so outside the +-3e-5 band the fast decision equals the golden OR;
// in-band pairs rerun the exact R7 chain from sp.
// R10-R13 lessons: store pattern/NT/burst-depth all ~neutral; grouped-band
// epilogue regressed; R13 (50.3us) is the base.
// R14 change: fold trick min(a,dom-a) = hd - |a-hd| (abs mods are free VOP3
// input modifiers; hd=0.5*dom exact) -> 6 ops/pair for the fold instead of 9;
// band check as single |d2m-RR|<=EPS compare. ~25% fewer fast-path VALU ops.

__global__ __launch_bounds__(256) void gg_shift_kernel(
    const float* __restrict__ pos, const float* __restrict__ dom,
    float4* __restrict__ sp, int n)
{
#pragma clang fp contract(off)
    int i = blockIdx.x * blockDim.x + threadIdx.x;
    if (i >= n) return;
    float x = pos[3 * i + 0];
    float y = pos[3 * i + 1];
    float z = pos[3 * i + 2];
    float dx = dom[0], dy = dom[1], dz = dom[2];
#pragma unroll
    for (int k = 0; k < 4; ++k) {
        float sx, sy, sz;
        if (k == 0) {
            sx = x; sy = y; sz = z;
        } else {
            float f = 0.25f * (float)k;
            sx = fmodf(x + f * dx, dx);
            sy = fmodf(y + f * dy, dy);
            sz = fmodf(z + f * dz, dz);
        }
        float sq = ((sx * sx) + (sy * sy)) + (sz * sz);
        sp[(size_t)i * 4 + k] = make_float4(sx, sy, sz, sq);
    }
}

// Tile: 32 i-rows x 256 j-cols per 256-thread block (R13 structure).
__global__ __launch_bounds__(256) void gg_adj_kernel(
    const float4* __restrict__ sp, const float* __restrict__ dom,
    int* __restrict__ out, int n)
{
    const int tid = threadIdx.x;
    const int tj = tid & 63;
    const int ti = tid >> 6;
    const int jbase = blockIdx.x * 256 + tj * 4;
    const int ibase = blockIdx.y * 32;
    const bool hasdiag = ((blockIdx.y >> 3) == blockIdx.x);

    const float hd0 = 0.5f * dom[0];   // exact (power-of-2 scale)
    const float hd1 = 0.5f * dom[1];
    const float hd2 = 0.5f * dom[2];

    __shared__ float4 si[32][4];   // i-tile: 4 variants (slow path needs all)
    for (int t = tid; t < 128; t += 256)
        si[t >> 2][t & 3] = sp[(size_t)(ibase + (t >> 2)) * 4 + (t & 3)];

    float4 jd0[4];                 // j-side raw coords (variant 0)
#pragma unroll
    for (int p = 0; p < 4; ++p)
        jd0[p] = sp[(size_t)(jbase + p) * 4 + 0];

    __syncthreads();

    const float RR  = 0.01f;       // f32(0.1*0.1)
    const float EPS = 3e-5f;       // band half-width

    int4 resbuf[8];                // all results, then burst-store

#pragma unroll
    for (int iter = 0; iter < 8; ++iter) {
        const int irow = iter * 4 + ti;
        const float4 i0 = si[irow][0];       // LDS broadcast, raw coords

        int* r = &resbuf[iter].x;
#pragma unroll
        for (int p = 0; p < 4; ++p) {
            // fold: min(|d|, dom-|d|) = hd - |(|d| - hd)|  (abs mods free)
            const float dxv = i0.x - jd0[p].x;
            const float dyv = i0.y - jd0[p].y;
            const float dzv = i0.z - jd0[p].z;
            const float tx = fabsf(dxv) - hd0;
            const float ty = fabsf(dyv) - hd1;
            const float tz = fabsf(dzv) - hd2;
            const float mx = hd0 - fabsf(tx);
            const float my = hd1 - fabsf(ty);
            const float mz = hd2 - fabsf(tz);
            const float d2m = mx * mx + my * my + mz * mz;  // contraction ok
            bool b = d2m <= RR;
            if (__builtin_expect(fabsf(d2m - RR) <= EPS, 0)) {
                // band: exact golden chain over all 4 variants (R7-proven)
#pragma clang fp contract(off)
                b = false;
#pragma unroll 1
                for (int k = 0; k < 4; ++k) {
                    const float4 iv = si[irow][k];
                    const float4 jv = sp[(size_t)(jbase + p) * 4 + k];
                    float dot = __builtin_fmaf(iv.z, jv.z,
                                __builtin_fmaf(iv.y, jv.y, iv.x * jv.x));
                    float d2 = (iv.w + jv.w) - (2.0f * dot);
                    if (d2 <= RR) b = true;
                }
            }
            r[p] = b ? 1 : 0;
        }
    }

    // Rare diagonal fixup (32 of 8192 blocks).
    if (hasdiag) {
#pragma unroll
        for (int iter = 0; iter < 8; ++iter) {
            const int i = ibase + iter * 4 + ti;
            if (i == jbase + 0) resbuf[iter].x = 0;
            if (i == jbase + 1) resbuf[iter].y = 0;
            if (i == jbase + 2) resbuf[iter].z = 0;
            if (i == jbase + 3) resbuf[iter].w = 0;
        }
    }

    // Burst: 8 back-to-back dwordx4 stores.
#pragma unroll
    for (int iter = 0; iter < 8; ++iter) {
        const int i = ibase + iter * 4 + ti;
        *reinterpret_cast<int4*>(&out[(size_t)i * n + jbase]) = resbuf[iter];
    }
}

extern "C" void kernel_launch(void* const* d_in, const int* in_sizes, int n_in,
                              void* d_out, int out_size, void* d_ws, size_t ws_size,
                              hipStream_t stream) {
    const float* pos = (const float*)d_in[0];   // [N,3] float32
    const float* dom = (const float*)d_in[1];   // [3] float32
    const int n = in_sizes[0] / 3;              // 8192

    float4* sp = (float4*)d_ws;                 // [N][4] float4 = 512 KB
    int* out = (int*)d_out;                     // [N,N] int32 0/1

    gg_shift_kernel<<<(n + 255) / 256, 256, 0, stream>>>(pos, dom, sp, n);

    dim3 grid(n / 256, n / 32);                 // (32, 256)
    gg_adj_kernel<<<grid, 256, 0, stream>>>(sp, dom, out, n);
}